// Round 2
// baseline (9309.734 us; speedup 1.0000x reference)
//
#include <hip/hip_runtime.h>
#include <math.h>

#define BT 256

// Problem constants: B=16, T=64, IN=256, H=512, N=256, W=64, R=4, NW=1, OUT=256
#define Bx 16
#define Tt 64
#define INx 256

__device__ __forceinline__ float sigm(float v) { return 1.0f / (1.0f + expf(-v)); }
__device__ __forceinline__ float oneplusf(float v) { return 1.0f + ((v > 15.0f) ? v : log1pf(expf(v))); }
__device__ __forceinline__ float4 ld4(const float* p) { return *reinterpret_cast<const float4*>(p); }

// ---- workspace layout (float offsets) ----
// h0:0 h1:8192 cst:16384 Mb:24576 usg:286720 lnk:290816 pr0:1339392 pr1:1343488
// wrb:1347584 wwb:1363968 rwb:1368064 nrm:1372160 itf:1376256 ers:1383792
// wvs:1384816 rso:1385840 mds:1385904 oh:1386096 bwp:1402480  (end 1435248 floats)
#define ZERO_FLOATS 1376256

__global__ __launch_bounds__(BT) void k_zero(float* __restrict__ ws) {
    int g = blockIdx.x * BT + threadIdx.x;
    for (int i = g; i < ZERO_FLOATS; i += gridDim.x * BT) ws[i] = 0.0f;
}

// grid 144: blocks 0..127 gates GEMM + LSTM; 128..143 finish out[t-1]
__global__ __launch_bounds__(BT)
void k_gates(const float* __restrict__ x,
             const float* __restrict__ W_ih, const float* __restrict__ W_hh,
             const float* __restrict__ b_ih, const float* __restrict__ b_hh,
             const float* __restrict__ W_out, const float* __restrict__ b_out,
             const float* __restrict__ hr, float* __restrict__ hw,
             float* __restrict__ cst, const float* __restrict__ rwb,
             const float* __restrict__ oh, float* __restrict__ out, int t)
{
    const int bl = blockIdx.x, tid = threadIdx.x;
    __shared__ float red[1024];
    if (bl < 128) {
        int pl = tid >> 2, ks = tid & 3;
        int p = bl * 64 + pl;
        int b = p & 15, j = p >> 4;
        float a0 = 0, a1 = 0, a2 = 0, a3 = 0;
        const float *src, *w0, *w1, *w2, *w3;
        if (ks < 2) {
            int kofs = ks * 256;
            src = (ks == 0) ? (x + (t * Bx + b) * INx) : (rwb + b * 256);
            w0 = W_ih + (j)        * 512 + kofs;
            w1 = W_ih + (j + 512)  * 512 + kofs;
            w2 = W_ih + (j + 1024) * 512 + kofs;
            w3 = W_ih + (j + 1536) * 512 + kofs;
        } else {
            int kofs = (ks - 2) * 256;
            src = hr + b * 512 + kofs;
            w0 = W_hh + (j)        * 512 + kofs;
            w1 = W_hh + (j + 512)  * 512 + kofs;
            w2 = W_hh + (j + 1024) * 512 + kofs;
            w3 = W_hh + (j + 1536) * 512 + kofs;
        }
        for (int kk = 0; kk < 256; kk += 4) {
            float4 iv = ld4(src + kk);
            float4 q0 = ld4(w0 + kk);
            a0 += iv.x * q0.x + iv.y * q0.y + iv.z * q0.z + iv.w * q0.w;
            float4 q1 = ld4(w1 + kk);
            a1 += iv.x * q1.x + iv.y * q1.y + iv.z * q1.z + iv.w * q1.w;
            float4 q2 = ld4(w2 + kk);
            a2 += iv.x * q2.x + iv.y * q2.y + iv.z * q2.z + iv.w * q2.w;
            float4 q3 = ld4(w3 + kk);
            a3 += iv.x * q3.x + iv.y * q3.y + iv.z * q3.z + iv.w * q3.w;
        }
        red[pl * 16 + 0 * 4 + ks] = a0;
        red[pl * 16 + 1 * 4 + ks] = a1;
        red[pl * 16 + 2 * 4 + ks] = a2;
        red[pl * 16 + 3 * 4 + ks] = a3;
        __syncthreads();
        if (ks == 0) {
            const float* rp = red + pl * 16;
            float gi = rp[0]  + rp[1]  + rp[2]  + rp[3]  + b_ih[j]        + b_hh[j];
            float gf = rp[4]  + rp[5]  + rp[6]  + rp[7]  + b_ih[j + 512]  + b_hh[j + 512];
            float gg = rp[8]  + rp[9]  + rp[10] + rp[11] + b_ih[j + 1024] + b_hh[j + 1024];
            float go = rp[12] + rp[13] + rp[14] + rp[15] + b_ih[j + 1536] + b_hh[j + 1536];
            float cv = cst[b * 512 + j];
            cv = sigm(gf) * cv + sigm(gi) * tanhf(gg);
            float hv = sigm(go) * tanhf(cv);
            cst[b * 512 + j] = cv;
            hw[b * 512 + j] = hv;
        }
    } else if (t > 0) {
        int b = bl - 128, o = tid;
        float acc = b_out[o];
        acc += oh[b * 256 + o] + oh[(16 + b) * 256 + o] + oh[(32 + b) * 256 + o] + oh[(48 + b) * 256 + o];
        const float* wrow = W_out + o * 768 + 512;
        const float* rwp = rwb + b * 256;
        for (int k = 0; k < 256; k += 4) {
            float4 w4 = ld4(wrow + k);
            acc += rwp[k] * w4.x + rwp[k + 1] * w4.y + rwp[k + 2] * w4.z + rwp[k + 3] * w4.w;
        }
        out[((t - 1) * Bx + b) * 256 + o] = acc;
    }
}

// grid 79: blocks 0..14 itf = h@W_int + b_int; 15..78 out_h partials
__global__ __launch_bounds__(BT)
void k_itf(const float* __restrict__ hw, const float* __restrict__ W_int,
           const float* __restrict__ b_int, float* __restrict__ itf,
           const float* __restrict__ W_out, float* __restrict__ oh)
{
    const int bl = blockIdx.x, tid = threadIdx.x;
    __shared__ float red[4096];
    if (bl < 15) {
        int jl = tid & 31, ks = tid >> 5;  // 8-way K split
        int j = bl * 32 + jl;
        float acc[16];
#pragma unroll
        for (int b = 0; b < 16; b++) acc[b] = 0.f;
        if (j < 471) {
            for (int k = ks * 64; k < ks * 64 + 64; ++k) {
                float wv = W_int[k * 471 + j];
#pragma unroll
                for (int b = 0; b < 16; b++) acc[b] += hw[b * 512 + k] * wv;
            }
        }
#pragma unroll
        for (int b = 0; b < 16; b++) red[tid * 16 + b] = acc[b];
        __syncthreads();
        int jl2 = tid & 31, bh = tid >> 5;
        int j2 = bl * 32 + jl2;
        for (int rep = 0; rep < 2; ++rep) {
            int b2 = bh + 8 * rep;
            if (j2 < 471) {
                float s = 0;
#pragma unroll
                for (int ksx = 0; ksx < 8; ksx++) s += red[(ksx * 32 + jl2) * 16 + b2];
                itf[b2 * 471 + j2] = s + b_int[j2];
            }
        }
    } else {
        int idx = bl - 15;
        int b = idx >> 2, ks = idx & 3;
        int o = tid;
        const float* wrow = W_out + o * 768 + ks * 128;
        const float* hb = hw + b * 512 + ks * 128;
        float acc = 0;
        for (int k = 0; k < 128; k += 4) {
            float4 w4 = ld4(wrow + k);
            acc += hb[k] * w4.x + hb[k + 1] * w4.y + hb[k + 2] * w4.z + hb[k + 3] * w4.w;
        }
        oh[(ks * 16 + b) * 256 + o] = acc;
    }
}

// grid 16: per-batch interface / usage / sort / alloc / cw / ww / prec
__global__ __launch_bounds__(BT)
void k_iface(const float* __restrict__ itf, const float* __restrict__ Mb,
             const float* __restrict__ nrm, float* __restrict__ usg,
             const float* __restrict__ wrb, float* __restrict__ wwb,
             const float* __restrict__ pr_r, float* __restrict__ pr_w,
             float* __restrict__ ers, float* __restrict__ wvs,
             float* __restrict__ rso, float* __restrict__ mds)
{
    const int b = blockIdx.x, tid = threadIdx.x;
    __shared__ float smem[1152];
    __shared__ int s_idx[256];
    float* s_keys = smem;         // 256
    float* s_cw   = smem + 256;
    float* s_al   = smem + 512;
    float* s_tmp  = smem + 768;
    float* s_wk   = smem + 1024;  // 64
    float* s_sc   = smem + 1088;  // scalars
    const float* it = itf + b * 471;

    if (tid < 4) {
        float m0 = it[459 + tid * 3], m1 = it[460 + tid * 3], m2 = it[461 + tid * 3];
        float mx3 = fmaxf(m0, fmaxf(m1, m2));
        float e0 = expf(m0 - mx3), e1 = expf(m1 - mx3), e2 = expf(m2 - mx3);
        float inv = 1.f / (e0 + e1 + e2);
        mds[(b * 4 + tid) * 3 + 0] = e0 * inv;
        mds[(b * 4 + tid) * 3 + 1] = e1 * inv;
        mds[(b * 4 + tid) * 3 + 2] = e2 * inv;
        rso[b * 4 + tid] = oneplusf(it[256 + tid]);
        s_sc[tid] = sigm(it[453 + tid]);  // free gates
    }
    if (tid == 4) s_sc[4] = sigm(it[457]);      // alloc gate
    if (tid == 5) s_sc[5] = sigm(it[458]);      // write gate
    if (tid == 6) s_sc[6] = oneplusf(it[324]);  // write strength
    if (tid < 64) {
        ers[b * 64 + tid] = sigm(it[325 + tid]);
        wvs[b * 64 + tid] = sigm(it[389 + tid]);
        s_wk[tid] = it[260 + tid];
    }
    __syncthreads();
    if (tid < 64) {
        float v = s_wk[tid] * s_wk[tid];
        for (int o2 = 32; o2 > 0; o2 >>= 1) v += __shfl_down(v, o2);
        if (tid == 0) s_sc[7] = sqrtf(v);  // ||write key||
    }
    __syncthreads();
    {
        int n = tid;
        float psi = 1.f;
#pragma unroll
        for (int r = 0; r < 4; r++) psi *= (1.f - s_sc[r] * wrb[b * 1024 + r * 256 + n]);
        float wwp = wwb[b * 256 + n];
        float u = usg[b * 256 + n];
        u = (u + wwp - u * wwp) * psi;
        usg[b * 256 + n] = u;
        s_keys[n] = u;
        s_idx[n] = n;
        const float* Mr = Mb + (b * 256 + n) * 64;
        float dot = 0;
        for (int w = 0; w < 64; w += 4) {
            float4 m4 = ld4(Mr + w);
            dot += m4.x * s_wk[w] + m4.y * s_wk[w + 1] + m4.z * s_wk[w + 2] + m4.w * s_wk[w + 3];
        }
        s_cw[n] = s_sc[6] * dot / ((nrm[b * 256 + n] + 1e-6f) * (s_sc[7] + 1e-6f));
    }
    __syncthreads();
    // softmax over n
    s_tmp[tid] = s_cw[tid];
    __syncthreads();
    for (int s2 = 128; s2 > 0; s2 >>= 1) { if (tid < s2) s_tmp[tid] = fmaxf(s_tmp[tid], s_tmp[tid + s2]); __syncthreads(); }
    float mx = s_tmp[0];
    __syncthreads();
    float ex = expf(s_cw[tid] - mx);
    s_tmp[tid] = ex;
    __syncthreads();
    for (int s2 = 128; s2 > 0; s2 >>= 1) { if (tid < s2) s_tmp[tid] += s_tmp[tid + s2]; __syncthreads(); }
    float cwv = ex / s_tmp[0];
    __syncthreads();
    s_cw[tid] = cwv;
    // bitonic sort ascending with index tie-break (== stable argsort)
    for (int kk2 = 2; kk2 <= 256; kk2 <<= 1) {
        for (int j2 = kk2 >> 1; j2 > 0; j2 >>= 1) {
            int ixj = tid ^ j2;
            if (ixj > tid) {
                float ka = s_keys[tid], kb = s_keys[ixj];
                int ia = s_idx[tid], ib = s_idx[ixj];
                bool up = ((tid & kk2) == 0);
                bool sw = up ? (kb < ka || (kb == ka && ib < ia))
                             : (ka < kb || (ka == kb && ia < ib));
                if (sw) { s_keys[tid] = kb; s_keys[ixj] = ka; s_idx[tid] = ib; s_idx[ixj] = ia; }
            }
            __syncthreads();
        }
    }
    // exclusive prefix product of sorted usage
    s_tmp[tid] = s_keys[tid];
    __syncthreads();
    for (int o2 = 1; o2 < 256; o2 <<= 1) {
        float pv = (tid >= o2) ? s_tmp[tid - o2] : 1.0f;
        __syncthreads();
        s_tmp[tid] *= pv;
        __syncthreads();
    }
    float excl = (tid == 0) ? 1.0f : s_tmp[tid - 1];
    float a_s = (1.0f - s_keys[tid]) * excl;
    s_al[s_idx[tid]] = a_s;
    __syncthreads();
    float ag = s_sc[4], wg = s_sc[5];
    float wwn = wg * (ag * s_al[tid] + (1.f - ag) * s_cw[tid]);
    wwb[b * 256 + tid] = wwn;
    s_tmp[tid] = wwn;
    __syncthreads();
    for (int s2 = 128; s2 > 0; s2 >>= 1) { if (tid < s2) s_tmp[tid] += s_tmp[tid + s2]; __syncthreads(); }
    float S = s_tmp[0];
    pr_w[b * 256 + tid] = (1.f - S) * pr_r[b * 256 + tid] + wwn;
}

// grid 144: blocks 0..127 link update + bwd partials; 128..143 M erase/write + norms
__global__ __launch_bounds__(BT)
void k_linkmem(const float* __restrict__ wwb, const float* __restrict__ pr_r,
               float* __restrict__ lnk, const float* __restrict__ wrb,
               float* __restrict__ bwp, float* __restrict__ Mb,
               const float* __restrict__ ers, const float* __restrict__ wvs,
               float* __restrict__ nrm)
{
    const int bl = blockIdx.x, tid = threadIdx.x;
    if (bl < 128) {
        int b = bl >> 3, ch = bl & 7;
        int ci = tid;
        float wwc = wwb[b * 256 + ci];
        float pco = pr_r[b * 256 + ci];
        float* Lb = lnk + b * 65536;
        float b0 = 0, b1 = 0, b2 = 0, b3 = 0;
        int r0 = ch * 32;
        for (int rr = 0; rr < 32; ++rr) {
            int ri = r0 + rr;
            float wwr = wwb[b * 256 + ri];
            float v = Lb[ri * 256 + ci];
            v = (1.f - wwr - wwc) * v + wwr * pco;
            if (ci == ri) v = 0.f;
            Lb[ri * 256 + ci] = v;
            b0 += v * wrb[b * 1024 + ri];
            b1 += v * wrb[b * 1024 + 256 + ri];
            b2 += v * wrb[b * 1024 + 512 + ri];
            b3 += v * wrb[b * 1024 + 768 + ri];
        }
        float* bp = bwp + ((b * 8 + ch) * 4) * 256;
        bp[ci] = b0; bp[256 + ci] = b1; bp[512 + ci] = b2; bp[768 + ci] = b3;
    } else {
        int b = bl - 128;
        int w = tid & 63, rg = tid >> 6;
        float er = ers[b * 64 + w], wv = wvs[b * 64 + w];
        for (int it2 = 0; it2 < 64; ++it2) {
            int n = rg + 4 * it2;
            float wwn = wwb[b * 256 + n];
            float m = Mb[(b * 256 + n) * 64 + w];
            m = m * (1.f - wwn * er) + wwn * wv;
            Mb[(b * 256 + n) * 64 + w] = m;
            float s = m * m;
            for (int o2 = 32; o2 > 0; o2 >>= 1) s += __shfl_down(s, o2);
            if (w == 0) nrm[b * 256 + n] = sqrtf(s);
        }
    }
}

// grid 64: per-(b,r): bwd sum, fwd, cr softmax, wr, read_words
__global__ __launch_bounds__(BT)
void k_read(const float* __restrict__ lnk, const float* __restrict__ bwp,
            const float* __restrict__ Mb, const float* __restrict__ nrm,
            const float* __restrict__ itf, const float* __restrict__ rso,
            const float* __restrict__ mds, float* __restrict__ wrb,
            float* __restrict__ rwb)
{
    const int bl = blockIdx.x, tid = threadIdx.x;
    __shared__ float smem[896];
    int b = bl >> 2, r = bl & 3;
    float* s_wr  = smem;        // 256
    float* s_tmp = smem + 512;  // 256
    float* s_key = smem + 768;  // 64
    float* s_sc  = smem + 840;
    s_wr[tid] = wrb[b * 1024 + r * 256 + tid];
    if (tid < 64) s_key[tid] = itf[b * 471 + r * 64 + tid];
    __syncthreads();
    if (tid < 64) {
        float v = s_key[tid] * s_key[tid];
        for (int o2 = 32; o2 > 0; o2 >>= 1) v += __shfl_down(v, o2);
        if (tid == 0) s_sc[0] = sqrtf(v);
    }
    __syncthreads();
    int n = tid;
    const float* bp = bwp + b * 8192 + r * 256 + n;
    float bwd_n = 0;
#pragma unroll
    for (int ch = 0; ch < 8; ++ch) bwd_n += bp[ch * 1024];
    const float* Lr = lnk + b * 65536 + n * 256;
    float fwd_n = 0;
    for (int j2 = 0; j2 < 256; j2 += 4) {
        float4 l4 = ld4(Lr + j2);
        fwd_n += l4.x * s_wr[j2] + l4.y * s_wr[j2 + 1] + l4.z * s_wr[j2 + 2] + l4.w * s_wr[j2 + 3];
    }
    const float* Mr = Mb + (b * 256 + n) * 64;
    float dot = 0;
    for (int w = 0; w < 64; w += 4) {
        float4 m4 = ld4(Mr + w);
        dot += m4.x * s_key[w] + m4.y * s_key[w + 1] + m4.z * s_key[w + 2] + m4.w * s_key[w + 3];
    }
    float simv = rso[b * 4 + r] * dot / ((nrm[b * 256 + n] + 1e-6f) * (s_sc[0] + 1e-6f));
    s_tmp[tid] = simv;
    __syncthreads();
    for (int s2 = 128; s2 > 0; s2 >>= 1) { if (tid < s2) s_tmp[tid] = fmaxf(s_tmp[tid], s_tmp[tid + s2]); __syncthreads(); }
    float mx = s_tmp[0];
    __syncthreads();
    float ex = expf(simv - mx);
    s_tmp[tid] = ex;
    __syncthreads();
    for (int s2 = 128; s2 > 0; s2 >>= 1) { if (tid < s2) s_tmp[tid] += s_tmp[tid + s2]; __syncthreads(); }
    float crv = ex / s_tmp[0];
    float mbv = mds[(b * 4 + r) * 3 + 0];
    float mfv = mds[(b * 4 + r) * 3 + 1];
    float mcv = mds[(b * 4 + r) * 3 + 2];
    float wrn = mbv * bwd_n + mfv * fwd_n + mcv * crv;
    wrb[b * 1024 + r * 256 + n] = wrn;
    __syncthreads();
    s_wr[tid] = wrn;
    __syncthreads();
    int w = tid & 63, gq = tid >> 6;
    float p = 0;
    const float* Mg = Mb + b * 256 * 64;
    for (int n2 = gq * 64; n2 < gq * 64 + 64; ++n2)
        p += s_wr[n2] * Mg[n2 * 64 + w];
    s_tmp[tid] = p;
    __syncthreads();
    if (tid < 64)
        rwb[b * 256 + r * 64 + tid] = s_tmp[tid] + s_tmp[tid + 64] + s_tmp[tid + 128] + s_tmp[tid + 192];
}

// grid 16: final out[T-1]
__global__ __launch_bounds__(BT)
void k_final(const float* __restrict__ oh, const float* __restrict__ W_out,
             const float* __restrict__ b_out, const float* __restrict__ rwb,
             float* __restrict__ out)
{
    int b = blockIdx.x, o = threadIdx.x;
    float acc = b_out[o];
    acc += oh[b * 256 + o] + oh[(16 + b) * 256 + o] + oh[(32 + b) * 256 + o] + oh[(48 + b) * 256 + o];
    const float* wrow = W_out + o * 768 + 512;
    const float* rwp = rwb + b * 256;
    for (int k = 0; k < 256; k += 4) {
        float4 w4 = ld4(wrow + k);
        acc += rwp[k] * w4.x + rwp[k + 1] * w4.y + rwp[k + 2] * w4.z + rwp[k + 3] * w4.w;
    }
    out[((Tt - 1) * Bx + b) * 256 + o] = acc;
}

extern "C" void kernel_launch(void* const* d_in, const int* in_sizes, int n_in,
                              void* d_out, int out_size, void* d_ws, size_t ws_size,
                              hipStream_t stream) {
    const float* x     = (const float*)d_in[0];
    const float* W_ih  = (const float*)d_in[1];
    const float* W_hh  = (const float*)d_in[2];
    const float* b_ih  = (const float*)d_in[3];
    const float* b_hh  = (const float*)d_in[4];
    const float* W_int = (const float*)d_in[5];
    const float* b_int = (const float*)d_in[6];
    const float* W_out = (const float*)d_in[7];
    const float* b_out = (const float*)d_in[8];
    float* outp = (float*)d_out;
    float* ws   = (float*)d_ws;

    float* h0  = ws + 0;
    float* h1  = ws + 8192;
    float* cst = ws + 16384;
    float* Mb  = ws + 24576;
    float* usg = ws + 286720;
    float* lnk = ws + 290816;
    float* pr0 = ws + 1339392;
    float* pr1 = ws + 1343488;
    float* wrb = ws + 1347584;
    float* wwb = ws + 1363968;
    float* rwb = ws + 1368064;
    float* nrm = ws + 1372160;
    float* itf = ws + 1376256;
    float* ers = ws + 1383792;
    float* wvs = ws + 1384816;
    float* rso = ws + 1385840;
    float* mds = ws + 1385904;
    float* oh  = ws + 1386096;
    float* bwp = ws + 1402480;
    (void)usg;

    k_zero<<<672, BT, 0, stream>>>(ws);
    for (int t = 0; t < Tt; ++t) {
        const float* hr = (t & 1) ? h1 : h0;
        float*       hw = (t & 1) ? h0 : h1;
        const float* pr_r = (t & 1) ? pr1 : pr0;
        float*       pr_w = (t & 1) ? pr0 : pr1;
        k_gates<<<144, BT, 0, stream>>>(x, W_ih, W_hh, b_ih, b_hh, W_out, b_out,
                                        hr, hw, cst, rwb, oh, outp, t);
        k_itf<<<79, BT, 0, stream>>>(hw, W_int, b_int, itf, W_out, oh);
        k_iface<<<16, BT, 0, stream>>>(itf, Mb, nrm, ws + 286720, wrb, wwb,
                                       pr_r, pr_w, ers, wvs, rso, mds);
        k_linkmem<<<144, BT, 0, stream>>>(wwb, pr_r, lnk, wrb, bwp, Mb, ers, wvs, nrm);
        k_read<<<64, BT, 0, stream>>>(lnk, bwp, Mb, nrm, itf, rso, mds, wrb, rwb);
    }
    k_final<<<16, BT, 0, stream>>>(oh, W_out, b_out, rwb, outp);
}